// Round 1
// baseline (91.265 us; speedup 1.0000x reference)
//
#include <hip/hip_runtime.h>

#define NS   88     // species
#define CCH  128    // channels
#define MTOT 136    // 34 monomial coeffs * 4 output components (0e, 1o x3)
#define GY   16     // stripes per species in main kernel

// ---------------- setup kernels ----------------

__global__ __launch_bounds__(256) void k_hist(const int* __restrict__ species,
                                              int* __restrict__ counts, int N) {
    int n = blockIdx.x * 256 + threadIdx.x;
    if (n < N) atomicAdd(&counts[species[n]], 1);
}

__global__ void k_scan(const int* __restrict__ counts, int* __restrict__ offsets,
                       int* __restrict__ cursor) {
    if (threadIdx.x == 0) {
        int acc = 0;
        for (int s = 0; s < NS; ++s) { offsets[s] = acc; cursor[s] = acc; acc += counts[s]; }
        offsets[NS] = acc;
    }
}

__global__ __launch_bounds__(256) void k_scatter(const int* __restrict__ species,
                                                 int* __restrict__ cursor,
                                                 int* __restrict__ list, int N) {
    int n = blockIdx.x * 256 + threadIdx.x;
    if (n < N) { int p = atomicAdd(&cursor[species[n]], 1); list[p] = n; }
}

// ---------------- coefficient table ----------------
// Layout: T[s][m][c], m in 0..135: rows 0..33 = 0e, rows 34+i*34+m = 1o component i.
// Within each 34: 0..19 cubic multisets (a<=b<=d loop order), 20..29 pairs (a<=b), 30..33 linear.

template <int K3, int I>
__device__ void build_table(const float* __restrict__ u3, const float* __restrict__ w3,
                            const float* __restrict__ u2, const float* __restrict__ w2,
                            const float* __restrict__ u1, const float* __restrict__ w1,
                            int s, int c, float* __restrict__ Tsc, int mbase) {
    float wk3[K3];
#pragma unroll
    for (int k = 0; k < K3; ++k) wk3[k] = w3[(s * K3 + k) * CCH + c];
    float wk2[2];
#pragma unroll
    for (int k = 0; k < 2; ++k) wk2[k] = w2[(s * 2 + k) * CCH + c];
    float wk1 = w1[s * CCH + c];

    // cubic: S3[m][i] = sum over distinct permutations of (a,b,d) of C3[perm][i],
    // computed as (sum over all 6 orderings)/rep, rep = product of multiplicities!.
    int m = 0;
#pragma unroll
    for (int a = 0; a < 4; ++a)
#pragma unroll
    for (int b = a; b < 4; ++b)
#pragma unroll
    for (int d = b; d < 4; ++d) {
        float acc[I];
#pragma unroll
        for (int i = 0; i < I; ++i) acc[i] = 0.f;
        const int P[6][3] = {{a,b,d},{a,d,b},{b,a,d},{b,d,a},{d,a,b},{d,b,a}};
#pragma unroll
        for (int p = 0; p < 6; ++p) {
            int base = ((P[p][0] * 4 + P[p][1]) * 4 + P[p][2]) * (K3 * I);
#pragma unroll
            for (int k = 0; k < K3; ++k)
#pragma unroll
            for (int i = 0; i < I; ++i)
                acc[i] += u3[base + k * I + i] * wk3[k];
        }
        float inv = (a == d) ? (1.f / 6.f) : ((a == b || b == d) ? 0.5f : 1.f);
#pragma unroll
        for (int i = 0; i < I; ++i) Tsc[(mbase + i * 34 + m) * CCH] = acc[i] * inv;
        ++m;
    }
    // quadratic
    int m2 = 0;
#pragma unroll
    for (int a = 0; a < 4; ++a)
#pragma unroll
    for (int b = a; b < 4; ++b) {
        float acc[I];
#pragma unroll
        for (int i = 0; i < I; ++i) acc[i] = 0.f;
#pragma unroll
        for (int k = 0; k < 2; ++k)
#pragma unroll
        for (int i = 0; i < I; ++i) {
            acc[i] += u2[((a * 4 + b) * 2 + k) * I + i] * wk2[k];
            if (a != b) acc[i] += u2[((b * 4 + a) * 2 + k) * I + i] * wk2[k];
        }
#pragma unroll
        for (int i = 0; i < I; ++i) Tsc[(mbase + i * 34 + 20 + m2) * CCH] = acc[i];
        ++m2;
    }
    // linear
#pragma unroll
    for (int d = 0; d < 4; ++d)
#pragma unroll
    for (int i = 0; i < I; ++i)
        Tsc[(mbase + i * 34 + 30 + d) * CCH] = u1[d * I + i] * wk1;
}

__global__ __launch_bounds__(128) void k_table(
    const float* u1_0e, const float* w1_0e, const float* u1_1o, const float* w1_1o,
    const float* u2_0e, const float* w2_0e, const float* u2_1o, const float* w2_1o,
    const float* u3_0e, const float* w3_0e, const float* u3_1o, const float* w3_1o,
    float* __restrict__ T) {
    int t = blockIdx.x * 128 + threadIdx.x;
    int s = t >> 7, c = t & 127;
    float* Tsc = T + (size_t)s * (MTOT * CCH) + c;
    build_table<4, 1>(u3_0e, w3_0e, u2_0e, w2_0e, u1_0e, w1_0e, s, c, Tsc, 0);
    build_table<6, 3>(u3_1o, w3_1o, u2_1o, w2_1o, u1_1o, w1_1o, s, c, Tsc, 34);
}

// ---------------- main kernel ----------------
// Block = 128 threads (one channel each). blockIdx.x = species, blockIdx.y = stripe.
// Coefficients for (s, c) held in VGPRs, reused across all atoms of the stripe.

__global__ __launch_bounds__(128, 1) void k_main(
    const float* __restrict__ x, const float* __restrict__ T,
    const int* __restrict__ list, const int* __restrict__ offsets,
    float* __restrict__ out) {
    int s = blockIdx.x;
    int c = threadIdx.x;
    int beg = offsets[s], end = offsets[s + 1];
    int t0 = beg + blockIdx.y;
    if (t0 >= end) return;

    const float* Tsc = T + (size_t)s * (MTOT * CCH) + c;
    float coef[MTOT];
#pragma unroll
    for (int m = 0; m < MTOT; ++m) coef[m] = Tsc[m * CCH];

    for (int t = t0; t < end; t += GY) {
        int n = list[t];
        float4 xv = *reinterpret_cast<const float4*>(x + (size_t)n * 512 + (c << 2));
        float xa[4] = {xv.x, xv.y, xv.z, xv.w};
        float mono[34];
        int q = 0;
#pragma unroll
        for (int a = 0; a < 4; ++a)
#pragma unroll
        for (int b = a; b < 4; ++b) { mono[20 + q] = xa[a] * xa[b]; ++q; }
        int m3 = 0;
#pragma unroll
        for (int a = 0; a < 4; ++a)
#pragma unroll
        for (int b = a; b < 4; ++b)
#pragma unroll
        for (int d = b; d < 4; ++d) { mono[m3] = mono[20 + (a * (7 - a)) / 2 + b] * xa[d]; ++m3; }
#pragma unroll
        for (int d = 0; d < 4; ++d) mono[30 + d] = xa[d];

        float o0 = 0.f, o1 = 0.f, o2 = 0.f, o3 = 0.f;
#pragma unroll
        for (int m = 0; m < 34; ++m) {
            float mv = mono[m];
            o0 = fmaf(coef[m],       mv, o0);
            o1 = fmaf(coef[34 + m],  mv, o1);
            o2 = fmaf(coef[68 + m],  mv, o2);
            o3 = fmaf(coef[102 + m], mv, o3);
        }
        float* orow = out + (size_t)n * 512;
        orow[c] = o0;
        orow[CCH + 3 * c + 0] = o1;
        orow[CCH + 3 * c + 1] = o2;
        orow[CCH + 3 * c + 2] = o3;
    }
}

// ---------------- launch ----------------

extern "C" void kernel_launch(void* const* d_in, const int* in_sizes, int n_in,
                              void* d_out, int out_size, void* d_ws, size_t ws_size,
                              hipStream_t stream) {
    const float* x     = (const float*)d_in[0];
    const float* u1_0e = (const float*)d_in[1];
    const float* w1_0e = (const float*)d_in[2];
    const float* u1_1o = (const float*)d_in[3];
    const float* w1_1o = (const float*)d_in[4];
    const float* u2_0e = (const float*)d_in[5];
    const float* w2_0e = (const float*)d_in[6];
    const float* u2_1o = (const float*)d_in[7];
    const float* w2_1o = (const float*)d_in[8];
    const float* u3_0e = (const float*)d_in[9];
    const float* w3_0e = (const float*)d_in[10];
    const float* u3_1o = (const float*)d_in[11];
    const float* w3_1o = (const float*)d_in[12];
    const int*   spec  = (const int*)d_in[13];
    int N = in_sizes[13];
    float* out = (float*)d_out;

    char* ws = (char*)d_ws;
    float* T     = (float*)ws;                                   // NS*MTOT*CCH floats
    size_t tbytes = (size_t)NS * MTOT * CCH * sizeof(float);
    int* counts  = (int*)(ws + tbytes);
    int* offsets = counts + NS;           // NS+1 ints
    int* cursor  = offsets + NS + 1;      // NS ints
    int* list    = cursor + NS;           // N ints

    hipMemsetAsync(counts, 0, NS * sizeof(int), stream);
    k_hist<<<(N + 255) / 256, 256, 0, stream>>>(spec, counts, N);
    k_scan<<<1, 64, 0, stream>>>(counts, offsets, cursor);
    k_scatter<<<(N + 255) / 256, 256, 0, stream>>>(spec, cursor, list, N);
    k_table<<<NS, 128, 0, stream>>>(u1_0e, w1_0e, u1_1o, w1_1o,
                                    u2_0e, w2_0e, u2_1o, w2_1o,
                                    u3_0e, w3_0e, u3_1o, w3_1o, T);
    k_main<<<dim3(NS, GY), 128, 0, stream>>>(x, T, list, offsets, out);
}

// Round 2
// 59.705 us; speedup vs baseline: 1.5286x; 1.5286x over previous
//
#include <hip/hip_runtime.h>

#define NS   88     // species
#define CCH  128    // channels
#define GY   16     // atom stripes per species in main kernel

// ---------------- coefficient table build (per s,c thread) ----------------
// T layout: [s][c][34][4]  -- row of 136 floats per (s,c).
// monomial index m: 0..19 cubic multisets (a<=b<=d), 20..29 pairs (a<=b), 30..33 linear.
// component i at T[...][m][IST+i]: IST=0 -> 0e (1 comp), IST=1 -> 1o (3 comps).

template <int K3, int IST, int I>
__device__ void build_table(const float* __restrict__ u3, const float* __restrict__ w3,
                            const float* __restrict__ u2, const float* __restrict__ w2,
                            const float* __restrict__ u1, const float* __restrict__ w1,
                            int s, int c, float* __restrict__ Tsc) {
    float wk3[K3];
#pragma unroll
    for (int k = 0; k < K3; ++k) wk3[k] = w3[(s * K3 + k) * CCH + c];
    float wk2[2];
#pragma unroll
    for (int k = 0; k < 2; ++k) wk2[k] = w2[(s * 2 + k) * CCH + c];
    float wk1 = w1[s * CCH + c];

    // cubic: symmetrized over distinct permutations = (sum all 6 orderings) / rep
    int m = 0;
#pragma unroll
    for (int a = 0; a < 4; ++a)
#pragma unroll
    for (int b = a; b < 4; ++b)
#pragma unroll
    for (int d = b; d < 4; ++d) {
        float acc[I];
#pragma unroll
        for (int i = 0; i < I; ++i) acc[i] = 0.f;
        const int P[6][3] = {{a,b,d},{a,d,b},{b,a,d},{b,d,a},{d,a,b},{d,b,a}};
#pragma unroll
        for (int p = 0; p < 6; ++p) {
            int base = ((P[p][0] * 4 + P[p][1]) * 4 + P[p][2]) * (K3 * I);
#pragma unroll
            for (int k = 0; k < K3; ++k)
#pragma unroll
            for (int i = 0; i < I; ++i)
                acc[i] += u3[base + k * I + i] * wk3[k];
        }
        float inv = (a == d) ? (1.f / 6.f) : ((a == b || b == d) ? 0.5f : 1.f);
#pragma unroll
        for (int i = 0; i < I; ++i) Tsc[m * 4 + IST + i] = acc[i] * inv;
        ++m;
    }
    // quadratic
    int m2 = 0;
#pragma unroll
    for (int a = 0; a < 4; ++a)
#pragma unroll
    for (int b = a; b < 4; ++b) {
        float acc[I];
#pragma unroll
        for (int i = 0; i < I; ++i) acc[i] = 0.f;
#pragma unroll
        for (int k = 0; k < 2; ++k)
#pragma unroll
        for (int i = 0; i < I; ++i) {
            acc[i] += u2[((a * 4 + b) * 2 + k) * I + i] * wk2[k];
            if (a != b) acc[i] += u2[((b * 4 + a) * 2 + k) * I + i] * wk2[k];
        }
#pragma unroll
        for (int i = 0; i < I; ++i) Tsc[(20 + m2) * 4 + IST + i] = acc[i];
        ++m2;
    }
    // linear
#pragma unroll
    for (int d = 0; d < 4; ++d)
#pragma unroll
    for (int i = 0; i < I; ++i)
        Tsc[(30 + d) * 4 + IST + i] = u1[d * I + i] * wk1;
}

// ---------------- fused setup kernel ----------------
// blocks [0, NS): per-species ordered compaction (no atomics, deterministic).
// blocks [NS, NS+44): coefficient table build, 256 threads = 2 (s,c)-rows... (t>>7 = s).

__global__ __launch_bounds__(256) void k_setup(
    const int* __restrict__ species, int N,
    const float* u1_0e, const float* w1_0e, const float* u1_1o, const float* w1_1o,
    const float* u2_0e, const float* w2_0e, const float* u2_1o, const float* w2_1o,
    const float* u3_0e, const float* w3_0e, const float* u3_1o, const float* w3_1o,
    float* __restrict__ T, int* __restrict__ offsets, int* __restrict__ list) {
    if (blockIdx.x < NS) {
        int s = blockIdx.x;
        int tid = threadIdx.x;
        int lane = tid & 63, w = tid >> 6;
        __shared__ int cnt[4];
        __shared__ int red[4];
        // pass 1: count atoms with species < s (== global offset of species s)
        int lt = 0;
        for (int n = tid; n < N; n += 256) lt += (species[n] < s);
#pragma unroll
        for (int o = 32; o; o >>= 1) lt += __shfl_down(lt, o, 64);
        if (lane == 0) red[w] = lt;
        __syncthreads();
        int pos = red[0] + red[1] + red[2] + red[3];
        int off0 = pos;
        // pass 2: ordered compaction of matching atom indices
        for (int base = 0; base < N; base += 256) {
            int n = base + tid;
            bool m = (n < N) && (species[n] == s);
            unsigned long long b = __ballot(m);
            int myrank = __popcll(b & ((1ull << lane) - 1));
            if (lane == 0) cnt[w] = __popcll(b);
            __syncthreads();
            int wbase = 0;
#pragma unroll
            for (int i = 0; i < 4; ++i) if (i < w) wbase += cnt[i];
            int ctot = cnt[0] + cnt[1] + cnt[2] + cnt[3];
            if (m) list[pos + wbase + myrank] = n;
            pos += ctot;
            __syncthreads();
        }
        if (tid == 0) {
            offsets[s] = off0;
            if (s == NS - 1) offsets[NS] = pos;
        }
    } else {
        int t = (blockIdx.x - NS) * 256 + threadIdx.x;   // 44*256 = 88*128 exactly
        int s = t >> 7, c = t & 127;
        float* Tsc = T + ((size_t)s * CCH + c) * 136;
        build_table<4, 0, 1>(u3_0e, w3_0e, u2_0e, w2_0e, u1_0e, w1_0e, s, c, Tsc);
        build_table<6, 1, 3>(u3_1o, w3_1o, u2_1o, w2_1o, u1_1o, w1_1o, s, c, Tsc);
    }
}

// ---------------- main kernel ----------------
// Block = 128 threads (one channel each), blockIdx.x = species, blockIdx.y = stripe.
// 34 x float4 coef rows in VGPRs, reused across the stripe's atoms; next atom's
// x prefetched during compute.

__global__ __launch_bounds__(128, 2) void k_main(
    const float* __restrict__ x, const float* __restrict__ T,
    const int* __restrict__ list, const int* __restrict__ offsets,
    float* __restrict__ out) {
    int s = blockIdx.x;
    int c = threadIdx.x;
    int beg = offsets[s], end = offsets[s + 1];
    int t = beg + (int)blockIdx.y;
    if (t >= end) return;

    const float4* Tsc = reinterpret_cast<const float4*>(T + ((size_t)s * CCH + c) * 136);
    float4 coef[34];
#pragma unroll
    for (int m = 0; m < 34; ++m) coef[m] = Tsc[m];

    int n = list[t];
    float4 xv = *reinterpret_cast<const float4*>(x + (size_t)n * 512 + (c << 2));

    while (true) {
        int tn = t + GY;
        bool more = tn < end;
        int nn = 0;
        float4 xn = make_float4(0.f, 0.f, 0.f, 0.f);
        if (more) {
            nn = list[tn];
            xn = *reinterpret_cast<const float4*>(x + (size_t)nn * 512 + (c << 2));
        }

        float xa[4] = {xv.x, xv.y, xv.z, xv.w};
        float mono[34];
        int q = 0;
#pragma unroll
        for (int a = 0; a < 4; ++a)
#pragma unroll
        for (int b = a; b < 4; ++b) { mono[20 + q] = xa[a] * xa[b]; ++q; }
        int m3 = 0;
#pragma unroll
        for (int a = 0; a < 4; ++a)
#pragma unroll
        for (int b = a; b < 4; ++b)
#pragma unroll
        for (int d = b; d < 4; ++d) { mono[m3] = mono[20 + (a * (7 - a)) / 2 + b] * xa[d]; ++m3; }
#pragma unroll
        for (int d = 0; d < 4; ++d) mono[30 + d] = xa[d];

        float o0 = 0.f, o1 = 0.f, o2 = 0.f, o3 = 0.f;
#pragma unroll
        for (int m = 0; m < 34; ++m) {
            float mv = mono[m];
            o0 = fmaf(coef[m].x, mv, o0);
            o1 = fmaf(coef[m].y, mv, o1);
            o2 = fmaf(coef[m].z, mv, o2);
            o3 = fmaf(coef[m].w, mv, o3);
        }
        float* orow = out + (size_t)n * 512;
        orow[c] = o0;
        orow[CCH + 3 * c + 0] = o1;
        orow[CCH + 3 * c + 1] = o2;
        orow[CCH + 3 * c + 2] = o3;

        if (!more) break;
        t = tn; n = nn; xv = xn;
    }
}

// ---------------- launch ----------------

extern "C" void kernel_launch(void* const* d_in, const int* in_sizes, int n_in,
                              void* d_out, int out_size, void* d_ws, size_t ws_size,
                              hipStream_t stream) {
    const float* x     = (const float*)d_in[0];
    const float* u1_0e = (const float*)d_in[1];
    const float* w1_0e = (const float*)d_in[2];
    const float* u1_1o = (const float*)d_in[3];
    const float* w1_1o = (const float*)d_in[4];
    const float* u2_0e = (const float*)d_in[5];
    const float* w2_0e = (const float*)d_in[6];
    const float* u2_1o = (const float*)d_in[7];
    const float* w2_1o = (const float*)d_in[8];
    const float* u3_0e = (const float*)d_in[9];
    const float* w3_0e = (const float*)d_in[10];
    const float* u3_1o = (const float*)d_in[11];
    const float* w3_1o = (const float*)d_in[12];
    const int*   spec  = (const int*)d_in[13];
    int N = in_sizes[13];
    float* out = (float*)d_out;

    char* ws = (char*)d_ws;
    float* T     = (float*)ws;                               // NS*CCH*136 floats
    size_t tbytes = (size_t)NS * CCH * 136 * sizeof(float);
    int* offsets = (int*)(ws + tbytes);                      // NS+1 ints
    int* list    = offsets + NS + 1;                         // N ints

    int table_blocks = (NS * CCH) / 256;                     // 44
    k_setup<<<NS + table_blocks, 256, 0, stream>>>(
        spec, N,
        u1_0e, w1_0e, u1_1o, w1_1o,
        u2_0e, w2_0e, u2_1o, w2_1o,
        u3_0e, w3_0e, u3_1o, w3_1o,
        T, offsets, list);
    k_main<<<dim3(NS, GY), 128, 0, stream>>>(x, T, list, offsets, out);
}